// Round 7
// baseline (450.966 us; speedup 1.0000x reference)
//
#include <hip/hip_runtime.h>
#include <hip/hip_bf16.h>
#include <math.h>

#define DIMC 1024
#define SEQ  2048
#define BATCH 4
#define NTOK 8192
#define HEADS 16
#define HD 64

typedef __attribute__((ext_vector_type(8))) short short8;
typedef __attribute__((ext_vector_type(4))) float f32x4;
typedef __attribute__((ext_vector_type(16))) float f32x16;
typedef __attribute__((ext_vector_type(2))) unsigned int uswap2;

#define GLDS(gp, lp) __builtin_amdgcn_global_load_lds(                        \
    (const __attribute__((address_space(1))) void*)(gp),                      \
    (__attribute__((address_space(3))) void*)(lp), 16, 0, 0)

__device__ __forceinline__ float bf2f(unsigned short u) {
    union { unsigned int i; float f; } v; v.i = ((unsigned int)u) << 16; return v.f;
}
__device__ __forceinline__ unsigned short f2bf(float f) {
    union { float f; unsigned int i; } v; v.f = f;
    unsigned int r = v.i + 0x7FFFu + ((v.i >> 16) & 1u);
    return (unsigned short)(r >> 16);
}
// HW packed f32x2 -> bf16x2: single v_cvt_pk_bf16_f32 (T12 recipe).
__device__ __forceinline__ unsigned int cvtpk(float a, float b) {
    unsigned int r;
    asm("v_cvt_pk_bf16_f32 %0, %1, %2" : "=v"(r) : "v"(a), "v"(b));
    return r;
}
__device__ __forceinline__ float fexp2(float x) {
#if __has_builtin(__builtin_amdgcn_exp2f)
    return __builtin_amdgcn_exp2f(x);
#else
    return exp2f(x);
#endif
}

// ---------------------------------------------------------------------------
// Fused prep (x4 vectorized): x cvt | 3 pointwise-weight cvts | masked-count.
// ---------------------------------------------------------------------------
__global__ __launch_bounds__(256)
void prep(const float* __restrict__ x,
          const float* __restrict__ pwq2, const float* __restrict__ pwk2,
          const float* __restrict__ pwv2, const int* __restrict__ mask,
          unsigned short* __restrict__ xb, unsigned short* __restrict__ pq,
          unsigned short* __restrict__ pk, unsigned short* __restrict__ pv,
          float* __restrict__ nmaskf)
{
    const size_t NE = (size_t)NTOK * DIMC;
    const size_t WE = (size_t)DIMC * DIMC;
    size_t i = ((size_t)blockIdx.x * 256 + threadIdx.x) * 4;
    const float* src = nullptr;
    unsigned short* dst = nullptr;
    if (i < NE) { src = x + i; dst = xb + i; }
    else if ((i -= NE) < WE) { src = pwq2 + i; dst = pq + i; }
    else if ((i -= WE) < WE) { src = pwk2 + i; dst = pk + i; }
    else if ((i -= WE) < WE) { src = pwv2 + i; dst = pv + i; }
    else {
        // masked-token count per batch (token index i, wave fully within one b)
        i -= WE;
        int4 m = *(const int4*)(mask + i);
        int cnt = (m.x == 0) + (m.y == 0) + (m.z == 0) + (m.w == 0);
#pragma unroll
        for (int off = 32; off; off >>= 1) cnt += __shfl_down(cnt, off, 64);
        if ((threadIdx.x & 63) == 0 && cnt)
            atomicAdd(&nmaskf[i >> 11], (float)cnt);
        return;
    }
    float4 v = *(const float4*)src;
    ushort4 o;
    o.x = f2bf(v.x); o.y = f2bf(v.y); o.z = f2bf(v.z); o.w = f2bf(v.w);
    *(ushort4*)dst = o;
}

// ---------------------------------------------------------------------------
// W [in][out] fp32 -> Wt [out][in] bf16, batched over 4 weights (z)
// ---------------------------------------------------------------------------
__global__ __launch_bounds__(256)
void transpose_cvt4(const float* __restrict__ W0, const float* __restrict__ W1,
                    const float* __restrict__ W2, const float* __restrict__ W3,
                    unsigned short* __restrict__ T0, unsigned short* __restrict__ T1,
                    unsigned short* __restrict__ T2, unsigned short* __restrict__ T3)
{
    int z = blockIdx.z;
    const float* W = z == 0 ? W0 : z == 1 ? W1 : z == 2 ? W2 : W3;
    unsigned short* Wt = z == 0 ? T0 : z == 1 ? T1 : z == 2 ? T2 : T3;
    __shared__ float T[32][33];
    int i0 = blockIdx.y * 32, o0 = blockIdx.x * 32;
    int c = threadIdx.x & 31, r4 = threadIdx.x >> 5;
#pragma unroll
    for (int p = 0; p < 4; ++p) {
        int r = r4 + p * 8;
        T[r][c] = W[(size_t)(i0 + r) * DIMC + o0 + c];
    }
    __syncthreads();
#pragma unroll
    for (int p = 0; p < 4; ++p) {
        int r = r4 + p * 8;
        Wt[(size_t)(o0 + r) * DIMC + i0 + c] = f2bf(T[c][r]);
    }
}

// ---------------------------------------------------------------------------
// bf16 MFMA GEMM core v5: 32x32x16 MFMA, BK=64, DOUBLE-BUFFERED with the T3
// minimum-2-phase order: issue next tile's 8 GLDS BEFORE computing current
// tile, ONE __syncthreads per K-step (== vmcnt(0)+barrier, compiler-safe).
// Loads get the whole ds_read+MFMA span to land; barrier count halves vs v4.
// NO sched_barrier(0), NO counted vmcnt (m141/R2 lessons). LDS 64 KB.
// 128B-row LDS, 8-slot XOR chunk swizzle (conflict-free b128, R5-verified).
// C/D layout: col=lane&31, row=(reg&3)+8*(reg>>2)+4*(lane>>5).
// ---------------------------------------------------------------------------
template<bool SILU, bool F32OUT>
__device__ __forceinline__
void gemm_core(const unsigned short* __restrict__ A,
               const unsigned short* __restrict__ Bt,
               const float* __restrict__ bias, void* __restrict__ Cout,
               int m0, int n0)
{
    __shared__ unsigned short As[2][128 * 64];
    __shared__ unsigned short Bs[2][128 * 64];
    const int tid = threadIdx.x;
    const int lane = tid & 63;
    const int l32 = lane & 31, hi = lane >> 5;
    const int wave = tid >> 6;
    const int wm = (wave & 1) * 64, wn = (wave >> 1) * 64;
    const int K = DIMC, N = DIMC;

    f32x16 acc[2][2];
#pragma unroll
    for (int tm = 0; tm < 2; ++tm)
#pragma unroll
        for (int tn = 0; tn < 2; ++tn) acc[tm][tn] = (f32x16)(0.0f);

    // staging: 1024 16B-chunk slots per matrix; thread covers slots
    // {tid, 256+tid, 512+tid, 768+tid}. slot s -> row=s>>3, cslot=s&7;
    // LDS dest = s*16B (linear); global source chunk = cslot ^ (row&7).
    int srow[4], ssrc[4], sdst[4];
#pragma unroll
    for (int p = 0; p < 4; ++p) {
        int s = p * 256 + tid;
        srow[p] = s >> 3;
        ssrc[p] = ((s & 7) ^ (srow[p] & 7)) * 8;
        sdst[p] = s * 8;
    }

    auto stage = [&](int buf, int k0) {
#pragma unroll
        for (int p = 0; p < 4; ++p)
            GLDS(A  + (size_t)(m0 + srow[p]) * K + k0 + ssrc[p], &As[buf][sdst[p]]);
#pragma unroll
        for (int p = 0; p < 4; ++p)
            GLDS(Bt + (size_t)(n0 + srow[p]) * K + k0 + ssrc[p], &Bs[buf][sdst[p]]);
    };

    stage(0, 0);          // prologue
    __syncthreads();      // drains prologue loads, publishes buf0

    auto body = [&](int k0, int cur) {
        if (k0 + 64 < K) stage(cur ^ 1, k0 + 64);   // prefetch FIRST
#pragma unroll
        for (int ks = 0; ks < 4; ++ks) {
            const int cb = ks * 2 + hi;              // k-chunk index 0..7
            short8 af[2], bf[2];
#pragma unroll
            for (int tm = 0; tm < 2; ++tm) {
                int row = wm + tm * 32 + l32;
                int slot = cb ^ (row & 7);
                af[tm] = *(const short8*)(&As[cur][row * 64 + slot * 8]);
            }
#pragma unroll
            for (int tn = 0; tn < 2; ++tn) {
                int row = wn + tn * 32 + l32;
                int slot = cb ^ (row & 7);
                bf[tn] = *(const short8*)(&Bs[cur][row * 64 + slot * 8]);
            }
#pragma unroll
            for (int tm = 0; tm < 2; ++tm)
#pragma unroll
                for (int tn = 0; tn < 2; ++tn)
                    acc[tm][tn] = __builtin_amdgcn_mfma_f32_32x32x16_bf16(
                        af[tm], bf[tn], acc[tm][tn], 0, 0, 0);
        }
        __syncthreads();   // drains prefetch (vmcnt 0) + publishes; reads of
                           // cur are complete (consumed by MFMAs above)
    };

    for (int k0 = 0; k0 < K; k0 += 128) {
        body(k0, 0);
        body(k0 + 64, 1);
    }

#pragma unroll
    for (int tn = 0; tn < 2; ++tn) {
        int ncol = n0 + wn + tn * 32 + l32;
        float bval = bias[ncol];
#pragma unroll
        for (int tm = 0; tm < 2; ++tm) {
#pragma unroll
            for (int r = 0; r < 16; ++r) {
                int mrow = m0 + wm + tm * 32 + (r & 3) + 8 * (r >> 2) + 4 * hi;
                float v = acc[tm][tn][r] + bval;
                if (SILU) v = v / (1.0f + __expf(-v));
                if (F32OUT)
                    ((float*)Cout)[(size_t)mrow * N + ncol] = v;
                else
                    ((unsigned short*)Cout)[(size_t)mrow * N + ncol] = f2bf(v);
            }
        }
    }
}

// XCD-aware bijective chunked swizzle (T1): consecutive remapped tiles land
// on the same XCD's L2 (HW round-robins linear wgid % 8). Valid: nwg % 8 == 0.
__device__ __forceinline__ int xcd_swz(int lin, int nwg) {
    return (lin & 7) * (nwg >> 3) + (lin >> 3);
}

__global__ __launch_bounds__(256)
void gemm_qkv(const unsigned short* A,
              const unsigned short* B0, const unsigned short* B1, const unsigned short* B2,
              const float* b0, const float* b1, const float* b2,
              unsigned short* C0, unsigned short* C1, unsigned short* C2)
{
    const int gy = NTOK / 128;                       // 64
    int lin = blockIdx.x + 8 * (blockIdx.y + gy * blockIdx.z);
    int t = xcd_swz(lin, 8 * gy * 3);
    int zz = t / (8 * gy); int rem = t - zz * 8 * gy;
    int m0 = (rem >> 3) * 128, n0 = (rem & 7) * 128;
    gemm_core<true, false>(A, zz == 0 ? B0 : zz == 1 ? B1 : B2,
                           zz == 0 ? b0 : zz == 1 ? b1 : b2,
                           zz == 0 ? C0 : zz == 1 ? C1 : C2, m0, n0);
}

__global__ __launch_bounds__(256)
void gemm_pw(const unsigned short* A0, const unsigned short* A1, const unsigned short* A2,
             const unsigned short* B0, const unsigned short* B1, const unsigned short* B2,
             const float* b0, const float* b1, const float* b2,
             unsigned short* C0, unsigned short* C1, unsigned short* C2)
{
    const int gy = NTOK / 128;
    int lin = blockIdx.x + 8 * (blockIdx.y + gy * blockIdx.z);
    int t = xcd_swz(lin, 8 * gy * 3);
    int zz = t / (8 * gy); int rem = t - zz * 8 * gy;
    int m0 = (rem >> 3) * 128, n0 = (rem & 7) * 128;
    gemm_core<false, false>(zz == 0 ? A0 : zz == 1 ? A1 : A2,
                            zz == 0 ? B0 : zz == 1 ? B1 : B2,
                            zz == 0 ? b0 : zz == 1 ? b1 : b2,
                            zz == 0 ? C0 : zz == 1 ? C1 : C2, m0, n0);
}

__global__ __launch_bounds__(256)
void gemm_wo(const unsigned short* A, const unsigned short* Bt,
             const float* bias, float* C)
{
    const int gy = NTOK / 128;
    int lin = blockIdx.x + 8 * blockIdx.y;
    int t = xcd_swz(lin, 8 * gy);
    int m0 = (t >> 3) * 128, n0 = (t & 7) * 128;
    gemm_core<false, true>(A, Bt, bias, C, m0, n0);
}

// ---------------------------------------------------------------------------
// Depthwise conv k=3 pad=1 over seq + bias, 8 channels/thread (short8),
// batched over q/k/v (blockIdx.y)
// ---------------------------------------------------------------------------
__global__ __launch_bounds__(256)
void dwconv3(const unsigned short* __restrict__ qb, const unsigned short* __restrict__ kb,
             const unsigned short* __restrict__ vb,
             const float* __restrict__ dwq, const float* __restrict__ dwbq,
             const float* __restrict__ dwk, const float* __restrict__ dwbk,
             const float* __restrict__ dwv, const float* __restrict__ dwbv,
             unsigned short* __restrict__ o0, unsigned short* __restrict__ o1,
             unsigned short* __restrict__ o2)
{
    int z = blockIdx.y;
    const unsigned short* X = z == 0 ? qb : z == 1 ? kb : vb;
    const float* dw  = z == 0 ? dwq  : z == 1 ? dwk  : dwv;
    const float* dwb = z == 0 ? dwbq : z == 1 ? dwbk : dwbv;
    unsigned short* Y = z == 0 ? o0 : z == 1 ? o1 : o2;

    int i8 = (blockIdx.x * 256 + threadIdx.x) * 8;
    int c = i8 & (DIMC - 1);
    int s = (i8 >> 10) & (SEQ - 1);
    short8 zero = {};
    short8 xc8 = *(const short8*)(X + i8);
    short8 xm8 = (s > 0)       ? *(const short8*)(X + i8 - DIMC) : zero;
    short8 xp8 = (s < SEQ - 1) ? *(const short8*)(X + i8 + DIMC) : zero;
    short8 y;
#pragma unroll
    for (int j = 0; j < 8; ++j) {
        float w0 = dw[(c + j) * 3 + 0], w1 = dw[(c + j) * 3 + 1], w2 = dw[(c + j) * 3 + 2];
        float r = fmaf(w0, bf2f((unsigned short)xm8[j]),
                  fmaf(w1, bf2f((unsigned short)xc8[j]),
                  fmaf(w2, bf2f((unsigned short)xp8[j]), dwb[c + j])));
        y[j] = (short)f2bf(r);
    }
    *(short8*)(Y + i8) = y;
}

// ---------------------------------------------------------------------------
// Per-token L2 normalize IN PLACE (scales folded into bf16 q/k).
// y=0: q gets 0.125*log2e/||q|| ; y=1: k gets mask/||k|| (masked K row -> 0,
// so its score is exactly 0 and p = exp2(0) = 1, corrected via nmask in attn).
// ---------------------------------------------------------------------------
__global__ __launch_bounds__(256)
void rownorms(unsigned short* __restrict__ qb, unsigned short* __restrict__ kb,
              const int* __restrict__ mask)
{
    unsigned short* X = (blockIdx.y ? kb : qb) + (size_t)blockIdx.x * DIMC;
    ushort4 v = ((const ushort4*)X)[threadIdx.x];
    float f0 = bf2f(v.x), f1 = bf2f(v.y), f2 = bf2f(v.z), f3 = bf2f(v.w);
    float s = f0 * f0 + f1 * f1 + f2 * f2 + f3 * f3;
#pragma unroll
    for (int off = 32; off; off >>= 1) s += __shfl_down(s, off, 64);
    __shared__ float part[4];
    if ((threadIdx.x & 63) == 0) part[threadIdx.x >> 6] = s;
    __syncthreads();
    float tot = part[0] + part[1] + part[2] + part[3];
    float post = blockIdx.y ? (mask[blockIdx.x] ? 1.0f : 0.0f)
                            : 0.125f * 1.44269504088896f;
    float inv = post / fmaxf(sqrtf(tot), 1e-12f);
    ushort4 o;
    o.x = f2bf(f0 * inv); o.y = f2bf(f1 * inv);
    o.z = f2bf(f2 * inv); o.w = f2bf(f3 * inv);
    ((ushort4*)X)[threadIdx.x] = o;
}

// ---------------------------------------------------------------------------
// V [B,S,C] bf16 -> Vt [B*H][64][SEQ] bf16 (per-head transpose), masked V rows
// zeroed so they contribute nothing to P@V.
// ---------------------------------------------------------------------------
__global__ __launch_bounds__(256)
void vtrans(const unsigned short* __restrict__ V, const int* __restrict__ mask,
            unsigned short* __restrict__ Vt)
{
    __shared__ unsigned short T[64][65];
    int st = blockIdx.x, bh = blockIdx.y;
    int b = bh >> 4, h = bh & 15;
    int tid = threadIdx.x;
#pragma unroll
    for (int t = 0; t < 16; ++t) {
        int o = t * 256 + tid; int r = o >> 6, c = o & 63;
        int srow = b * SEQ + st * 64 + r;
        T[r][c] = mask[srow] ? V[(size_t)srow * DIMC + h * HD + c] : (unsigned short)0;
    }
    __syncthreads();
#pragma unroll
    for (int t = 0; t < 16; ++t) {
        int o = t * 256 + tid; int r = o >> 6, c = o & 63;
        Vt[(size_t)bh * HD * SEQ + (size_t)r * SEQ + st * 64 + c] = T[c][r];
    }
}

// ---------------------------------------------------------------------------
// Flash attention v8: v7 + intra-wave MFMA/VALU pipelining. Both q-halves'
// QK^T MFMA clusters are issued back-to-back into the matrix pipe (independent
// sacc register sets); the softmax VALU (exp/cvt_pk/permlane) of g0 then
// executes WHILE g1's QK MFMAs are still running, and exp(g1) overlaps PV(g0).
// Removes the per-g serialization that capped v7 at MfmaUtil 35 / VALU 33.
// +32 VGPR for the second live sacc set (~160, still 2 blocks/CU).
// ---------------------------------------------------------------------------
__global__ __launch_bounds__(256, 2)
void attn_mfma8(const unsigned short* __restrict__ Q,
                const unsigned short* __restrict__ Km,
                const unsigned short* __restrict__ Vt,
                const float* __restrict__ nmaskf,
                unsigned short* __restrict__ O)
{
    __shared__ unsigned short Ksb[2][64 * 64];   // [k][d], chunk-swizzled
    __shared__ unsigned short Vsb[2][64 * 64];   // [d][k], chunk-swizzled
    const int tid = threadIdx.x, lane = tid & 63, wave = tid >> 6;
    const int l32 = lane & 31, hi = lane >> 5;
    // XCD swizzle: grid (8, 64) -> each XCD gets a contiguous bh chunk.
    int lin = blockIdx.x + 8 * blockIdx.y;
    int t0 = xcd_swz(lin, 8 * BATCH * HEADS);
    const int qt = t0 & 7, bh = t0 >> 3;
    const int b = bh >> 4, h = bh & 15;
    const size_t qkbase = (size_t)b * SEQ * DIMC + (size_t)h * HD;
    const size_t vtbase = (size_t)bh * HD * SEQ;
    const int qrowbase = qt * 256 + wave * 64;   // wave owns 64 q rows
    const int NT = SEQ / 64;

    // Q B-fragments (loop-invariant), two q-halves g=0,1 (rows +g*32)
    short8 aq[2][4];
#pragma unroll
    for (int g = 0; g < 2; ++g)
#pragma unroll
        for (int d = 0; d < 4; ++d)
            aq[g][d] = *(const short8*)(Q + qkbase +
                (size_t)(qrowbase + g * 32 + l32) * DIMC + d * 16 + hi * 8);

    short8 vone;
#pragma unroll
    for (int i = 0; i < 8; ++i) vone[i] = (short)0x3F80;   // bf16 1.0

    // staging slot geometry (linear LDS dest, pre-swizzled global source)
    const int sA = tid,        rA = sA >> 3, cA = (sA & 7) ^ (rA & 7);
    const int sB = 256 + tid,  rB = sB >> 3, cB = (sB & 7) ^ (rB & 7);

    const unsigned short* KmP = Km + qkbase;
    const unsigned short* VtP = Vt + vtbase;

    // prologue: stage tile 0 into buffer 0
    GLDS(KmP + (size_t)rA * DIMC + cA * 8, Ksb[0] + sA * 8);
    GLDS(KmP + (size_t)rB * DIMC + cB * 8, Ksb[0] + sB * 8);
    GLDS(VtP + (size_t)rA * SEQ + cA * 8,  Vsb[0] + sA * 8);
    GLDS(VtP + (size_t)rB * SEQ + cB * 8,  Vsb[0] + sB * 8);

    f32x16 oacc[2][2], lacc[2];
#pragma unroll
    for (int g = 0; g < 2; ++g) {
        oacc[g][0] = (f32x16)(0.0f); oacc[g][1] = (f32x16)(0.0f);
        lacc[g] = (f32x16)(0.0f);
    }

    auto body = [&](int kt, int cur) {
        __syncthreads();   // publishes buffer `cur`

        if (kt + 1 < NT) {
            const unsigned short* kn = KmP + (size_t)(kt + 1) * 64 * DIMC;
            const unsigned short* vn = VtP + (size_t)(kt + 1) * 64;
            GLDS(kn + (size_t)rA * DIMC + cA * 8, Ksb[cur ^ 1] + sA * 8);
            GLDS(kn + (size_t)rB * DIMC + cB * 8, Ksb[cur ^ 1] + sB * 8);
            GLDS(vn + (size_t)rA * SEQ + cA * 8,  Vsb[cur ^ 1] + sA * 8);
            GLDS(vn + (size_t)rB * SEQ + cB * 8,  Vsb[cur ^ 1] + sB * 8);
        }

        const unsigned short* Ks = Ksb[cur];
        const unsigned short* Vs = Vsb[cur];

        // hoist ALL K A-frags and V B-frags ONCE: reused by both q-halves.
        short8 ak[2][4], bv[4][2];
#pragma unroll
        for (int t = 0; t < 2; ++t) {
            const int row = t * 32 + l32, sw = row & 7;
#pragma unroll
            for (int d = 0; d < 4; ++d)
                ak[t][d] = *(const short8*)(Ks + row * 64 + (((d * 2 + hi) ^ sw)) * 8);
        }
#pragma unroll
        for (int s = 0; s < 4; ++s)
#pragma unroll
            for (int td = 0; td < 2; ++td) {
                const int row = td * 32 + l32, sw = row & 7;
                bv[s][td] = *(const short8*)(Vs + row * 64 + (((s * 2 + hi) ^ sw)) * 8);
            }

        // QK^T for BOTH q-halves, issued back-to-back (independent sacc sets):
        // g1's MFMAs execute while g0's softmax VALU runs below.
        f32x16 sacc[2][2];
        sacc[0][0] = (f32x16)(0.0f); sacc[0][1] = (f32x16)(0.0f);
        sacc[1][0] = (f32x16)(0.0f); sacc[1][1] = (f32x16)(0.0f);
        __builtin_amdgcn_s_setprio(1);
#pragma unroll
        for (int g = 0; g < 2; ++g)
#pragma unroll
            for (int t = 0; t < 2; ++t)
#pragma unroll
                for (int d = 0; d < 4; ++d)
                    sacc[g][t] = __builtin_amdgcn_mfma_f32_32x32x16_bf16(
                        ak[t][d], aq[g][d], sacc[g][t], 0, 0, 0);
        __builtin_amdgcn_s_setprio(0);

#pragma unroll
        for (int g = 0; g < 2; ++g) {
            // softmax: p = exp2(s) (scales folded into Q/K; mask folded into
            // K=0 rows -> p=1, corrected via nmask at epilogue)
#pragma unroll
            for (int t = 0; t < 2; ++t)
#pragma unroll
                for (int r = 0; r < 16; ++r)
                    sacc[g][t][r] = fexp2(sacc[g][t][r]);

            // P -> PV A-frags in-register (cvt_pk + permlane32_swap), PV + l.
            // PV(g0) MFMAs overlap exp(g1) VALU automatically (program order).
#pragma unroll
            for (int s = 0; s < 4; ++s) {
                const int t = s >> 1, u8 = (s & 1) * 8;
                unsigned int a0 = cvtpk(sacc[g][t][u8 + 0], sacc[g][t][u8 + 1]);
                unsigned int b0 = cvtpk(sacc[g][t][u8 + 4], sacc[g][t][u8 + 5]);
                unsigned int a1 = cvtpk(sacc[g][t][u8 + 2], sacc[g][t][u8 + 3]);
                unsigned int b1 = cvtpk(sacc[g][t][u8 + 6], sacc[g][t][u8 + 7]);
                uswap2 r0 = __builtin_amdgcn_permlane32_swap(a0, b0, false, false);
                uswap2 r1 = __builtin_amdgcn_permlane32_swap(a1, b1, false, false);
                union { unsigned int u[4]; short8 v; } pw;
                pw.u[0] = r0.x; pw.u[1] = r1.x; pw.u[2] = r0.y; pw.u[3] = r1.y;
                const short8 pa = pw.v;

                __builtin_amdgcn_s_setprio(1);
#pragma unroll
                for (int td = 0; td < 2; ++td)
                    oacc[g][td] = __builtin_amdgcn_mfma_f32_32x32x16_bf16(
                        pa, bv[s][td], oacc[g][td], 0, 0, 0);
                lacc[g] = __builtin_amdgcn_mfma_f32_32x32x16_bf16(
                    pa, vone, lacc[g], 0, 0, 0);
                __builtin_amdgcn_s_setprio(0);
            }
        }
    };

    for (int kt = 0; kt < NT; kt += 2) {
        body(kt, 0);
        body(kt + 1, 1);
    }

    // epilogue: lacc rows == oacc rows (same A-frags) -> no shuffles.
    // masked k columns contributed p=1 to lacc -> subtract per-batch count.
    const float nm = nmaskf[b];
#pragma unroll
    for (int g = 0; g < 2; ++g)
#pragma unroll
        for (int r = 0; r < 16; ++r) {
            float inv = 1.0f / (lacc[g][r] - nm);
            int grow = qrowbase + g * 32 + (r & 3) + 8 * (r >> 2) + 4 * hi;
#pragma unroll
            for (int t = 0; t < 2; ++t)
                O[(size_t)(b * SEQ + grow) * DIMC + h * HD + t * 32 + l32] =
                    f2bf(oacc[g][t][r] * inv);
        }
}

// ---------------------------------------------------------------------------
extern "C" void kernel_launch(void* const* d_in, const int* in_sizes, int n_in,
                              void* d_out, int out_size, void* d_ws, size_t ws_size,
                              hipStream_t stream)
{
    const float* x    = (const float*)d_in[0];
    const int*   mask = (const int*)  d_in[1];
    const float* wq   = (const float*)d_in[2];
    const float* bq   = (const float*)d_in[3];
    const float* dwq  = (const float*)d_in[4];
    const float* dwbq = (const float*)d_in[5];
    const float* pwq  = (const float*)d_in[6];
    const float* pwbq = (const float*)d_in[7];
    const float* wk   = (const float*)d_in[8];
    const float* bk   = (const float*)d_in[9];
    const float* dwk  = (const float*)d_in[10];
    const float* dwbk = (const float*)d_in[11];
    const float* pwk  = (const float*)d_in[12];
    const float* pwbk = (const float*)d_in[13];
    const float* wv   = (const float*)d_in[14];
    const float* bv   = (const float*)d_in[15];
    const float* dwv  = (const float*)d_in[16];
    const float* dwbv = (const float*)d_in[17];
    const float* pwv  = (const float*)d_in[18];
    const float* pwbv = (const float*)d_in[19];
    const float* wo   = (const float*)d_in[20];
    const float* bo   = (const float*)d_in[21];

    float* out = (float*)d_out;
    const size_t NE = (size_t)NTOK * DIMC;
    const size_t WE = (size_t)DIMC * DIMC;
    unsigned short* xb  = (unsigned short*)d_ws;   // x bf16; later dwconv-q out; later attn out
    unsigned short* qb  = xb + NE;
    unsigned short* kb  = qb + NE;
    unsigned short* vb  = kb + NE;
    unsigned short* tbA = vb + NE;
    unsigned short* tbB = tbA + NE;
    unsigned short* vt  = tbB + NE;
    unsigned short* wtq = vt + NE;
    unsigned short* wtk = wtq + WE;
    unsigned short* wtv = wtk + WE;
    unsigned short* wto = wtv + WE;
    unsigned short* pq  = wto + WE;
    unsigned short* pk  = pq + WE;
    unsigned short* pv  = pk + WE;
    float* nmaskf = (float*)(pv + WE);

    const dim3 tgrid(32, 32, 4);
    const dim3 ggrid3(DIMC / 128, NTOK / 128, 3);
    const dim3 ggrid(DIMC / 128, NTOK / 128);
    const dim3 vgrid(SEQ / 64, BATCH * HEADS);
    const dim3 agrid(SEQ / 256, BATCH * HEADS);
    const int pblk = (int)((NE + 3 * WE + NTOK) / 4 / 256);
    const int dblk = (int)(NE / 8 / 256);

    hipMemsetAsync(nmaskf, 0, BATCH * sizeof(float), stream);
    prep<<<pblk, 256, 0, stream>>>(x, pwq, pwk, pwv, mask, xb, pq, pk, pv, nmaskf);
    transpose_cvt4<<<tgrid, 256, 0, stream>>>(wq, wk, wv, wo, wtq, wtk, wtv, wto);

    // q/k/v = silu(x @ w + b), batched
    gemm_qkv<<<ggrid3, 256, 0, stream>>>(xb, wtq, wtk, wtv, bq, bk, bv, qb, kb, vb);

    // depthwise (batched) -> {xb, tbA, tbB}; pointwise (batched) -> back to q/k/v
    dwconv3<<<dim3(dblk, 3), 256, 0, stream>>>(qb, kb, vb, dwq, dwbq, dwk, dwbk,
                                               dwv, dwbv, xb, tbA, tbB);
    gemm_pw<<<ggrid3, 256, 0, stream>>>(xb, tbA, tbB, pq, pk, pv,
                                        pwbq, pwbk, pwbv, qb, kb, vb);

    // in-place l2 normalize q (0.125*log2e folded) and k (mask folded)
    rownorms<<<dim3(NTOK, 2), 256, 0, stream>>>(qb, kb, mask);

    // V transpose (masked rows zeroed), attention (out -> xb), final projection
    vtrans<<<vgrid, 256, 0, stream>>>(vb, mask, vt);
    attn_mfma8<<<agrid, 256, 0, stream>>>(qb, kb, vt, nmaskf, xb);
    gemm_wo<<<ggrid, 256, 0, stream>>>(xb, wto, bo, out);
}

// Round 8
// 445.022 us; speedup vs baseline: 1.0134x; 1.0134x over previous
//
#include <hip/hip_runtime.h>
#include <hip/hip_bf16.h>
#include <math.h>

#define DIMC 1024
#define SEQ  2048
#define BATCH 4
#define NTOK 8192
#define HEADS 16
#define HD 64

typedef __attribute__((ext_vector_type(8))) short short8;
typedef __attribute__((ext_vector_type(4))) float f32x4;
typedef __attribute__((ext_vector_type(16))) float f32x16;
typedef __attribute__((ext_vector_type(2))) unsigned int uswap2;

#define GLDS(gp, lp) __builtin_amdgcn_global_load_lds(                        \
    (const __attribute__((address_space(1))) void*)(gp),                      \
    (__attribute__((address_space(3))) void*)(lp), 16, 0, 0)

__device__ __forceinline__ float bf2f(unsigned short u) {
    union { unsigned int i; float f; } v; v.i = ((unsigned int)u) << 16; return v.f;
}
__device__ __forceinline__ unsigned short f2bf(float f) {
    union { float f; unsigned int i; } v; v.f = f;
    unsigned int r = v.i + 0x7FFFu + ((v.i >> 16) & 1u);
    return (unsigned short)(r >> 16);
}
// HW packed f32x2 -> bf16x2: single v_cvt_pk_bf16_f32 (T12 recipe).
__device__ __forceinline__ unsigned int cvtpk(float a, float b) {
    unsigned int r;
    asm("v_cvt_pk_bf16_f32 %0, %1, %2" : "=v"(r) : "v"(a), "v"(b));
    return r;
}
__device__ __forceinline__ float fexp2(float x) {
#if __has_builtin(__builtin_amdgcn_exp2f)
    return __builtin_amdgcn_exp2f(x);
#else
    return exp2f(x);
#endif
}

// ---------------------------------------------------------------------------
// Fused prep (x4 vectorized): x cvt | 3 pointwise-weight cvts | masked-count.
// ---------------------------------------------------------------------------
__global__ __launch_bounds__(256)
void prep(const float* __restrict__ x,
          const float* __restrict__ pwq2, const float* __restrict__ pwk2,
          const float* __restrict__ pwv2, const int* __restrict__ mask,
          unsigned short* __restrict__ xb, unsigned short* __restrict__ pq,
          unsigned short* __restrict__ pk, unsigned short* __restrict__ pv,
          float* __restrict__ nmaskf)
{
    const size_t NE = (size_t)NTOK * DIMC;
    const size_t WE = (size_t)DIMC * DIMC;
    size_t i = ((size_t)blockIdx.x * 256 + threadIdx.x) * 4;
    const float* src = nullptr;
    unsigned short* dst = nullptr;
    if (i < NE) { src = x + i; dst = xb + i; }
    else if ((i -= NE) < WE) { src = pwq2 + i; dst = pq + i; }
    else if ((i -= WE) < WE) { src = pwk2 + i; dst = pk + i; }
    else if ((i -= WE) < WE) { src = pwv2 + i; dst = pv + i; }
    else {
        // masked-token count per batch (token index i, wave fully within one b)
        i -= WE;
        int4 m = *(const int4*)(mask + i);
        int cnt = (m.x == 0) + (m.y == 0) + (m.z == 0) + (m.w == 0);
#pragma unroll
        for (int off = 32; off; off >>= 1) cnt += __shfl_down(cnt, off, 64);
        if ((threadIdx.x & 63) == 0 && cnt)
            atomicAdd(&nmaskf[i >> 11], (float)cnt);
        return;
    }
    float4 v = *(const float4*)src;
    ushort4 o;
    o.x = f2bf(v.x); o.y = f2bf(v.y); o.z = f2bf(v.z); o.w = f2bf(v.w);
    *(ushort4*)dst = o;
}

// ---------------------------------------------------------------------------
// W [in][out] fp32 -> Wt [out][in] bf16, batched over 4 weights (z)
// ---------------------------------------------------------------------------
__global__ __launch_bounds__(256)
void transpose_cvt4(const float* __restrict__ W0, const float* __restrict__ W1,
                    const float* __restrict__ W2, const float* __restrict__ W3,
                    unsigned short* __restrict__ T0, unsigned short* __restrict__ T1,
                    unsigned short* __restrict__ T2, unsigned short* __restrict__ T3)
{
    int z = blockIdx.z;
    const float* W = z == 0 ? W0 : z == 1 ? W1 : z == 2 ? W2 : W3;
    unsigned short* Wt = z == 0 ? T0 : z == 1 ? T1 : z == 2 ? T2 : T3;
    __shared__ float T[32][33];
    int i0 = blockIdx.y * 32, o0 = blockIdx.x * 32;
    int c = threadIdx.x & 31, r4 = threadIdx.x >> 5;
#pragma unroll
    for (int p = 0; p < 4; ++p) {
        int r = r4 + p * 8;
        T[r][c] = W[(size_t)(i0 + r) * DIMC + o0 + c];
    }
    __syncthreads();
#pragma unroll
    for (int p = 0; p < 4; ++p) {
        int r = r4 + p * 8;
        Wt[(size_t)(o0 + r) * DIMC + i0 + c] = f2bf(T[c][r]);
    }
}

// ---------------------------------------------------------------------------
// bf16 MFMA GEMM core v6: DEPTH-3 COUNTED PIPELINE (T3+T4 done right).
// BM=256 BN=128 BK=64, 512 threads (8 waves: 4M x 2N), per-wave 64x64.
// 3 LDS buffers (144 KB). Per K-tile t:
//   stage tile t+2 -> buf((t+2)%3)         (6 GLDS; 18 in flight)
//   s_waitcnt vmcnt(12)                    (waits ONLY tile t's 6; 2 tiles stay
//                                           in flight across barriers - T4)
//   s_barrier                              (tile t resident for all waves)
//   16 MFMA + 16 ds_read_b128 from buf(t%3)
//   s_barrier                              (fences buf reuse; ds_reads are
//                                           complete here: compiler lgkmcnt
//                                           precedes each consuming MFMA)
// Loads get TWO compute-spans to land; vmcnt never drains mid-loop.
// Race invariant: stage into buf((t+2)%3) only after barrier B of iter t-1,
// which all waves passed after finishing reads of that same buffer.
// NO sched_barrier(0) (m141); asm memory clobbers only.
// 128B-row LDS, 8-slot XOR chunk swizzle. C/D layout as before.
// ---------------------------------------------------------------------------
template<bool SILU, bool F32OUT>
__device__ __forceinline__
void gemm_core(const unsigned short* __restrict__ A,
               const unsigned short* __restrict__ Bt,
               const float* __restrict__ bias, void* __restrict__ Cout,
               int m0, int n0)
{
    __shared__ unsigned short As[3 * 256 * 64];   // 96 KB
    __shared__ unsigned short Bs[3 * 128 * 64];   // 48 KB
    const int tid = threadIdx.x;
    const int lane = tid & 63;
    const int l32 = lane & 31, hi = lane >> 5;
    const int wave = tid >> 6;                    // 0..7
    const int wm = (wave >> 1) * 64, wn = (wave & 1) * 64;
    const int K = DIMC, N = DIMC;
    const int NT = K / 64;                        // 16

    f32x16 acc[2][2];
#pragma unroll
    for (int tm = 0; tm < 2; ++tm)
#pragma unroll
        for (int tn = 0; tn < 2; ++tn) acc[tm][tn] = (f32x16)(0.0f);

    // staging: A = 2048 chunks (4/thread), B = 1024 chunks (2/thread).
    // slot s -> row=s>>3, cslot=s&7; LDS dest linear s*16B; global source
    // chunk = cslot ^ (row&7)  (inverse of the read-side XOR).
    int arow[4], asrc[4], adst[4];
#pragma unroll
    for (int p = 0; p < 4; ++p) {
        int s = p * 512 + tid;
        arow[p] = s >> 3;
        asrc[p] = ((s & 7) ^ (arow[p] & 7)) * 8;
        adst[p] = s * 8;
    }
    int brow[2], bsrc[2], bdst[2];
#pragma unroll
    for (int p = 0; p < 2; ++p) {
        int s = p * 512 + tid;
        brow[p] = s >> 3;
        bsrc[p] = ((s & 7) ^ (brow[p] & 7)) * 8;
        bdst[p] = s * 8;
    }

    auto stage = [&](int buf, int kt) {
        const int k0 = kt * 64;
#pragma unroll
        for (int p = 0; p < 4; ++p)
            GLDS(A + (size_t)(m0 + arow[p]) * K + k0 + asrc[p],
                 As + buf * (256 * 64) + adst[p]);
#pragma unroll
        for (int p = 0; p < 2; ++p)
            GLDS(Bt + (size_t)(n0 + brow[p]) * K + k0 + bsrc[p],
                 Bs + buf * (128 * 64) + bdst[p]);
    };

    stage(0, 0);
    stage(1, 1);          // 12 loads in flight

    int buf = 0, nbuf = 2;
    for (int t = 0; t < NT; ++t) {
        if (t + 2 < NT) {
            stage(nbuf, t + 2);                                   // -> 18
            asm volatile("s_waitcnt vmcnt(12)" ::: "memory");     // tile t done
        } else if (t + 2 == NT) {
            asm volatile("s_waitcnt vmcnt(6)" ::: "memory");      // t=NT-2
        } else {
            asm volatile("s_waitcnt vmcnt(0)" ::: "memory");      // t=NT-1
        }
        __builtin_amdgcn_s_barrier();       // A: tile t resident for all waves
        asm volatile("" ::: "memory");      // pin ds_reads after barrier

        const unsigned short* Asb = As + buf * (256 * 64);
        const unsigned short* Bsb = Bs + buf * (128 * 64);
#pragma unroll
        for (int ks = 0; ks < 4; ++ks) {
            const int cb = ks * 2 + hi;      // k-chunk 0..7
            short8 af[2], bf[2];
#pragma unroll
            for (int tm = 0; tm < 2; ++tm) {
                int row = wm + tm * 32 + l32;
                af[tm] = *(const short8*)(Asb + row * 64 + ((cb ^ (row & 7)) * 8));
            }
#pragma unroll
            for (int tn = 0; tn < 2; ++tn) {
                int row = wn + tn * 32 + l32;
                bf[tn] = *(const short8*)(Bsb + row * 64 + ((cb ^ (row & 7)) * 8));
            }
#pragma unroll
            for (int tm = 0; tm < 2; ++tm)
#pragma unroll
                for (int tn = 0; tn < 2; ++tn)
                    acc[tm][tn] = __builtin_amdgcn_mfma_f32_32x32x16_bf16(
                        af[tm], bf[tn], acc[tm][tn], 0, 0, 0);
        }
        asm volatile("" ::: "memory");      // pin ds_reads before barrier
        __builtin_amdgcn_s_barrier();       // B: buf free for restage
        buf  = (buf  == 2) ? 0 : buf  + 1;
        nbuf = (nbuf == 2) ? 0 : nbuf + 1;
    }

#pragma unroll
    for (int tn = 0; tn < 2; ++tn) {
        int ncol = n0 + wn + tn * 32 + l32;
        float bval = bias[ncol];
#pragma unroll
        for (int tm = 0; tm < 2; ++tm) {
#pragma unroll
            for (int r = 0; r < 16; ++r) {
                int mrow = m0 + wm + tm * 32 + (r & 3) + 8 * (r >> 2) + 4 * hi;
                float v = acc[tm][tn][r] + bval;
                if (SILU) v = v / (1.0f + __expf(-v));
                if (F32OUT)
                    ((float*)Cout)[(size_t)mrow * N + ncol] = v;
                else
                    ((unsigned short*)Cout)[(size_t)mrow * N + ncol] = f2bf(v);
            }
        }
    }
}

// XCD-aware bijective chunked swizzle (T1): consecutive remapped tiles land
// on the same XCD's L2 (HW round-robins linear wgid % 8). Valid: nwg % 8 == 0.
__device__ __forceinline__ int xcd_swz(int lin, int nwg) {
    return (lin & 7) * (nwg >> 3) + (lin >> 3);
}

// grids: x = n-tiles (1024/128 = 8), y = m-tiles (8192/256 = 32), z = batch
__global__ __launch_bounds__(512, 2)
void gemm_qkv(const unsigned short* A,
              const unsigned short* B0, const unsigned short* B1, const unsigned short* B2,
              const float* b0, const float* b1, const float* b2,
              unsigned short* C0, unsigned short* C1, unsigned short* C2)
{
    const int gy = NTOK / 256;                       // 32
    int lin = blockIdx.x + 8 * (blockIdx.y + gy * blockIdx.z);
    int t = xcd_swz(lin, 8 * gy * 3);
    int zz = t / (8 * gy); int rem = t - zz * 8 * gy;
    int m0 = (rem >> 3) * 256, n0 = (rem & 7) * 128;
    gemm_core<true, false>(A, zz == 0 ? B0 : zz == 1 ? B1 : B2,
                           zz == 0 ? b0 : zz == 1 ? b1 : b2,
                           zz == 0 ? C0 : zz == 1 ? C1 : C2, m0, n0);
}

__global__ __launch_bounds__(512, 2)
void gemm_pw(const unsigned short* A0, const unsigned short* A1, const unsigned short* A2,
             const unsigned short* B0, const unsigned short* B1, const unsigned short* B2,
             const float* b0, const float* b1, const float* b2,
             unsigned short* C0, unsigned short* C1, unsigned short* C2)
{
    const int gy = NTOK / 256;
    int lin = blockIdx.x + 8 * (blockIdx.y + gy * blockIdx.z);
    int t = xcd_swz(lin, 8 * gy * 3);
    int zz = t / (8 * gy); int rem = t - zz * 8 * gy;
    int m0 = (rem >> 3) * 256, n0 = (rem & 7) * 128;
    gemm_core<false, false>(zz == 0 ? A0 : zz == 1 ? A1 : A2,
                            zz == 0 ? B0 : zz == 1 ? B1 : B2,
                            zz == 0 ? b0 : zz == 1 ? b1 : b2,
                            zz == 0 ? C0 : zz == 1 ? C1 : C2, m0, n0);
}

__global__ __launch_bounds__(512, 2)
void gemm_wo(const unsigned short* A, const unsigned short* Bt,
             const float* bias, float* C)
{
    const int gy = NTOK / 256;
    int lin = blockIdx.x + 8 * blockIdx.y;
    int t = xcd_swz(lin, 8 * gy);
    int m0 = (t >> 3) * 256, n0 = (t & 7) * 128;
    gemm_core<false, true>(A, Bt, bias, C, m0, n0);
}

// ---------------------------------------------------------------------------
// Depthwise conv k=3 pad=1 over seq + bias, 8 channels/thread (short8),
// batched over q/k/v (blockIdx.y)
// ---------------------------------------------------------------------------
__global__ __launch_bounds__(256)
void dwconv3(const unsigned short* __restrict__ qb, const unsigned short* __restrict__ kb,
             const unsigned short* __restrict__ vb,
             const float* __restrict__ dwq, const float* __restrict__ dwbq,
             const float* __restrict__ dwk, const float* __restrict__ dwbk,
             const float* __restrict__ dwv, const float* __restrict__ dwbv,
             unsigned short* __restrict__ o0, unsigned short* __restrict__ o1,
             unsigned short* __restrict__ o2)
{
    int z = blockIdx.y;
    const unsigned short* X = z == 0 ? qb : z == 1 ? kb : vb;
    const float* dw  = z == 0 ? dwq  : z == 1 ? dwk  : dwv;
    const float* dwb = z == 0 ? dwbq : z == 1 ? dwbk : dwbv;
    unsigned short* Y = z == 0 ? o0 : z == 1 ? o1 : o2;

    int i8 = (blockIdx.x * 256 + threadIdx.x) * 8;
    int c = i8 & (DIMC - 1);
    int s = (i8 >> 10) & (SEQ - 1);
    short8 zero = {};
    short8 xc8 = *(const short8*)(X + i8);
    short8 xm8 = (s > 0)       ? *(const short8*)(X + i8 - DIMC) : zero;
    short8 xp8 = (s < SEQ - 1) ? *(const short8*)(X + i8 + DIMC) : zero;
    short8 y;
#pragma unroll
    for (int j = 0; j < 8; ++j) {
        float w0 = dw[(c + j) * 3 + 0], w1 = dw[(c + j) * 3 + 1], w2 = dw[(c + j) * 3 + 2];
        float r = fmaf(w0, bf2f((unsigned short)xm8[j]),
                  fmaf(w1, bf2f((unsigned short)xc8[j]),
                  fmaf(w2, bf2f((unsigned short)xp8[j]), dwb[c + j])));
        y[j] = (short)f2bf(r);
    }
    *(short8*)(Y + i8) = y;
}

// ---------------------------------------------------------------------------
// Per-token L2 normalize IN PLACE (scales folded into bf16 q/k).
// y=0: q gets 0.125*log2e/||q|| ; y=1: k gets mask/||k|| (masked K row -> 0,
// so its score is exactly 0 and p = exp2(0) = 1, corrected via nmask in attn).
// ---------------------------------------------------------------------------
__global__ __launch_bounds__(256)
void rownorms(unsigned short* __restrict__ qb, unsigned short* __restrict__ kb,
              const int* __restrict__ mask)
{
    unsigned short* X = (blockIdx.y ? kb : qb) + (size_t)blockIdx.x * DIMC;
    ushort4 v = ((const ushort4*)X)[threadIdx.x];
    float f0 = bf2f(v.x), f1 = bf2f(v.y), f2 = bf2f(v.z), f3 = bf2f(v.w);
    float s = f0 * f0 + f1 * f1 + f2 * f2 + f3 * f3;
#pragma unroll
    for (int off = 32; off; off >>= 1) s += __shfl_down(s, off, 64);
    __shared__ float part[4];
    if ((threadIdx.x & 63) == 0) part[threadIdx.x >> 6] = s;
    __syncthreads();
    float tot = part[0] + part[1] + part[2] + part[3];
    float post = blockIdx.y ? (mask[blockIdx.x] ? 1.0f : 0.0f)
                            : 0.125f * 1.44269504088896f;
    float inv = post / fmaxf(sqrtf(tot), 1e-12f);
    ushort4 o;
    o.x = f2bf(f0 * inv); o.y = f2bf(f1 * inv);
    o.z = f2bf(f2 * inv); o.w = f2bf(f3 * inv);
    ((ushort4*)X)[threadIdx.x] = o;
}

// ---------------------------------------------------------------------------
// V [B,S,C] bf16 -> Vt [B*H][64][SEQ] bf16 (per-head transpose), masked V rows
// zeroed so they contribute nothing to P@V.
// ---------------------------------------------------------------------------
__global__ __launch_bounds__(256)
void vtrans(const unsigned short* __restrict__ V, const int* __restrict__ mask,
            unsigned short* __restrict__ Vt)
{
    __shared__ unsigned short T[64][65];
    int st = blockIdx.x, bh = blockIdx.y;
    int b = bh >> 4, h = bh & 15;
    int tid = threadIdx.x;
#pragma unroll
    for (int t = 0; t < 16; ++t) {
        int o = t * 256 + tid; int r = o >> 6, c = o & 63;
        int srow = b * SEQ + st * 64 + r;
        T[r][c] = mask[srow] ? V[(size_t)srow * DIMC + h * HD + c] : (unsigned short)0;
    }
    __syncthreads();
#pragma unroll
    for (int t = 0; t < 16; ++t) {
        int o = t * 256 + tid; int r = o >> 6, c = o & 63;
        Vt[(size_t)bh * HD * SEQ + (size_t)r * SEQ + st * 64 + c] = T[c][r];
    }
}

// ---------------------------------------------------------------------------
// Flash attention v7 (R6-verified, reverted from v8's spilling variant):
// 64 q-rows per wave, K/V frags hoisted once per body, in-register softmax.
// ---------------------------------------------------------------------------
__global__ __launch_bounds__(256, 2)
void attn_mfma7(const unsigned short* __restrict__ Q,
                const unsigned short* __restrict__ Km,
                const unsigned short* __restrict__ Vt,
                const float* __restrict__ nmaskf,
                unsigned short* __restrict__ O)
{
    __shared__ unsigned short Ksb[2][64 * 64];   // [k][d], chunk-swizzled
    __shared__ unsigned short Vsb[2][64 * 64];   // [d][k], chunk-swizzled
    const int tid = threadIdx.x, lane = tid & 63, wave = tid >> 6;
    const int l32 = lane & 31, hi = lane >> 5;
    int lin = blockIdx.x + 8 * blockIdx.y;
    int t0 = xcd_swz(lin, 8 * BATCH * HEADS);
    const int qt = t0 & 7, bh = t0 >> 3;
    const int b = bh >> 4, h = bh & 15;
    const size_t qkbase = (size_t)b * SEQ * DIMC + (size_t)h * HD;
    const size_t vtbase = (size_t)bh * HD * SEQ;
    const int qrowbase = qt * 256 + wave * 64;   // wave owns 64 q rows
    const int NT = SEQ / 64;

    short8 aq[2][4];
#pragma unroll
    for (int g = 0; g < 2; ++g)
#pragma unroll
        for (int d = 0; d < 4; ++d)
            aq[g][d] = *(const short8*)(Q + qkbase +
                (size_t)(qrowbase + g * 32 + l32) * DIMC + d * 16 + hi * 8);

    short8 vone;
#pragma unroll
    for (int i = 0; i < 8; ++i) vone[i] = (short)0x3F80;   // bf16 1.0

    const int sA = tid,        rA = sA >> 3, cA = (sA & 7) ^ (rA & 7);
    const int sB = 256 + tid,  rB = sB >> 3, cB = (sB & 7) ^ (rB & 7);

    const unsigned short* KmP = Km + qkbase;
    const unsigned short* VtP = Vt + vtbase;

    GLDS(KmP + (size_t)rA * DIMC + cA * 8, Ksb[0] + sA * 8);
    GLDS(KmP + (size_t)rB * DIMC + cB * 8, Ksb[0] + sB * 8);
    GLDS(VtP + (size_t)rA * SEQ + cA * 8,  Vsb[0] + sA * 8);
    GLDS(VtP + (size_t)rB * SEQ + cB * 8,  Vsb[0] + sB * 8);

    f32x16 oacc[2][2], lacc[2];
#pragma unroll
    for (int g = 0; g < 2; ++g) {
        oacc[g][0] = (f32x16)(0.0f); oacc[g][1] = (f32x16)(0.0f);
        lacc[g] = (f32x16)(0.0f);
    }

    auto body = [&](int kt, int cur) {
        __syncthreads();   // publishes buffer `cur`

        if (kt + 1 < NT) {
            const unsigned short* kn = KmP + (size_t)(kt + 1) * 64 * DIMC;
            const unsigned short* vn = VtP + (size_t)(kt + 1) * 64;
            GLDS(kn + (size_t)rA * DIMC + cA * 8, Ksb[cur ^ 1] + sA * 8);
            GLDS(kn + (size_t)rB * DIMC + cB * 8, Ksb[cur ^ 1] + sB * 8);
            GLDS(vn + (size_t)rA * SEQ + cA * 8,  Vsb[cur ^ 1] + sA * 8);
            GLDS(vn + (size_t)rB * SEQ + cB * 8,  Vsb[cur ^ 1] + sB * 8);
        }

        const unsigned short* Ks = Ksb[cur];
        const unsigned short* Vs = Vsb[cur];

        // hoist ALL K A-frags and V B-frags ONCE: reused by both q-halves.
        short8 ak[2][4], bv[4][2];
#pragma unroll
        for (int t = 0; t < 2; ++t) {
            const int row = t * 32 + l32, sw = row & 7;
#pragma unroll
            for (int d = 0; d < 4; ++d)
                ak[t][d] = *(const short8*)(Ks + row * 64 + (((d * 2 + hi) ^ sw)) * 8);
        }
#pragma unroll
        for (int s = 0; s < 4; ++s)
#pragma unroll
            for (int td = 0; td < 2; ++td) {
                const int row = td * 32 + l32, sw = row & 7;
                bv[s][td] = *(const short8*)(Vs + row * 64 + (((s * 2 + hi) ^ sw)) * 8);
            }

#pragma unroll
        for (int g = 0; g < 2; ++g) {
            f32x16 sacc[2];
            sacc[0] = (f32x16)(0.0f); sacc[1] = (f32x16)(0.0f);
            __builtin_amdgcn_s_setprio(1);
#pragma unroll
            for (int t = 0; t < 2; ++t)
#pragma unroll
                for (int d = 0; d < 4; ++d)
                    sacc[t] = __builtin_amdgcn_mfma_f32_32x32x16_bf16(
                        ak[t][d], aq[g][d], sacc[t], 0, 0, 0);
            __builtin_amdgcn_s_setprio(0);

#pragma unroll
            for (int t = 0; t < 2; ++t)
#pragma unroll
                for (int r = 0; r < 16; ++r)
                    sacc[t][r] = fexp2(sacc[t][r]);

#pragma unroll
            for (int s = 0; s < 4; ++s) {
                const int t = s >> 1, u8 = (s & 1) * 8;
                unsigned int a0 = cvtpk(sacc[t][u8 + 0], sacc[t][u8 + 1]);
                unsigned int b0 = cvtpk(sacc[t][u8 + 4], sacc[t][u8 + 5]);
                unsigned int a1 = cvtpk(sacc[t][u8 + 2], sacc[t][u8 + 3]);
                unsigned int b1 = cvtpk(sacc[t][u8 + 6], sacc[t][u8 + 7]);
                uswap2 r0 = __builtin_amdgcn_permlane32_swap(a0, b0, false, false);
                uswap2 r1 = __builtin_amdgcn_permlane32_swap(a1, b1, false, false);
                union { unsigned int u[4]; short8 v; } pw;
                pw.u[0] = r0.x; pw.u[1] = r1.x; pw.u[2] = r0.y; pw.u[3] = r1.y;
                const short8 pa = pw.v;

                __builtin_amdgcn_s_setprio(1);
#pragma unroll
                for (int td = 0; td < 2; ++td)
                    oacc[g][td] = __builtin_amdgcn_mfma_f32_32x32x16_bf16(
                        pa, bv[s][td], oacc[g][td], 0, 0, 0);
                lacc[g] = __builtin_amdgcn_mfma_f32_32x32x16_bf16(
                    pa, vone, lacc[g], 0, 0, 0);
                __builtin_amdgcn_s_setprio(0);
            }
        }
    };

    for (int kt = 0; kt < NT; kt += 2) {
        body(kt, 0);
        body(kt + 1, 1);
    }

    const float nm = nmaskf[b];
#pragma unroll
    for (int g = 0; g < 2; ++g)
#pragma unroll
        for (int r = 0; r < 16; ++r) {
            float inv = 1.0f / (lacc[g][r] - nm);
            int grow = qrowbase + g * 32 + (r & 3) + 8 * (r >> 2) + 4 * hi;
#pragma unroll
            for (int t = 0; t < 2; ++t)
                O[(size_t)(b * SEQ + grow) * DIMC + h * HD + t * 32 + l32] =
                    f2bf(oacc[g][t][r] * inv);
        }
}

// ---------------------------------------------------------------------------
extern "C" void kernel_launch(void* const* d_in, const int* in_sizes, int n_in,
                              void* d_out, int out_size, void* d_ws, size_t ws_size,
                              hipStream_t stream)
{
    const float* x    = (const float*)d_in[0];
    const int*   mask = (const int*)  d_in[1];
    const float* wq   = (const float*)d_in[2];
    const float* bq   = (const float*)d_in[3];
    const float* dwq  = (const float*)d_in[4];
    const float* dwbq = (const float*)d_in[5];
    const float* pwq  = (const float*)d_in[6];
    const float* pwbq = (const float*)d_in[7];
    const float* wk   = (const float*)d_in[8];
    const float* bk   = (const float*)d_in[9];
    const float* dwk  = (const float*)d_in[10];
    const float* dwbk = (const float*)d_in[11];
    const float* pwk  = (const float*)d_in[12];
    const float* pwbk = (const float*)d_in[13];
    const float* wv   = (const float*)d_in[14];
    const float* bv   = (const float*)d_in[15];
    const float* dwv  = (const float*)d_in[16];
    const float* dwbv = (const float*)d_in[17];
    const float* pwv  = (const float*)d_in[18];
    const float* pwbv = (const float*)d_in[19];
    const float* wo   = (const float*)d_in[20];
    const float* bo   = (const float*)d_in[21];

    float* out = (float*)d_out;
    const size_t NE = (size_t)NTOK * DIMC;
    const size_t WE = (size_t)DIMC * DIMC;
    unsigned short* xb  = (unsigned short*)d_ws;   // x bf16; later dwconv-q out; later attn out
    unsigned short* qb  = xb + NE;
    unsigned short* kb  = qb + NE;
    unsigned short* vb  = kb + NE;
    unsigned short* tbA = vb + NE;
    unsigned short* tbB = tbA + NE;
    unsigned short* vt  = tbB + NE;
    unsigned short* wtq = vt + NE;
    unsigned short* wtk = wtq + WE;
    unsigned short* wtv = wtk + WE;
    unsigned short* wto = wtv + WE;
    unsigned short* pq  = wto + WE;
    unsigned short* pk  = pq + WE;
    unsigned short* pv  = pk + WE;
    float* nmaskf = (float*)(pv + WE);

    const dim3 tgrid(32, 32, 4);
    const dim3 ggrid3(DIMC / 128, NTOK / 256, 3);
    const dim3 ggrid(DIMC / 128, NTOK / 256);
    const dim3 vgrid(SEQ / 64, BATCH * HEADS);
    const dim3 agrid(SEQ / 256, BATCH * HEADS);
    const int pblk = (int)((NE + 3 * WE + NTOK) / 4 / 256);
    const int dblk = (int)(NE / 8 / 256);

    hipMemsetAsync(nmaskf, 0, BATCH * sizeof(float), stream);
    prep<<<pblk, 256, 0, stream>>>(x, pwq, pwk, pwv, mask, xb, pq, pk, pv, nmaskf);
    transpose_cvt4<<<tgrid, 256, 0, stream>>>(wq, wk, wv, wo, wtq, wtk, wtv, wto);

    // q/k/v = silu(x @ w + b), batched
    gemm_qkv<<<ggrid3, 512, 0, stream>>>(xb, wtq, wtk, wtv, bq, bk, bv, qb, kb, vb);

    // depthwise (batched) -> {xb, tbA, tbB}; pointwise (batched) -> back to q/k/v
    dwconv3<<<dim3(dblk, 3), 256, 0, stream>>>(qb, kb, vb, dwq, dwbq, dwk, dwbk,
                                               dwv, dwbv, xb, tbA, tbB);
    gemm_pw<<<ggrid3, 512, 0, stream>>>(xb, tbA, tbB, pq, pk, pv,
                                        pwbq, pwbk, pwbv, qb, kb, vb);

    // in-place l2 normalize q (0.125*log2e folded) and k (mask folded)
    rownorms<<<dim3(NTOK, 2), 256, 0, stream>>>(qb, kb, mask);

    // V transpose (masked rows zeroed), attention (out -> xb), final projection
    vtrans<<<vgrid, 256, 0, stream>>>(vb, mask, vt);
    attn_mfma7<<<agrid, 256, 0, stream>>>(qb, kb, vt, nmaskf, xb);
    gemm_wo<<<ggrid, 512, 0, stream>>>(xb, wto, bo, out);
}

// Round 9
// 425.410 us; speedup vs baseline: 1.0601x; 1.0461x over previous
//
#include <hip/hip_runtime.h>
#include <hip/hip_bf16.h>
#include <math.h>

#define DIMC 1024
#define SEQ  2048
#define BATCH 4
#define NTOK 8192
#define HEADS 16
#define HD 64

typedef __attribute__((ext_vector_type(8))) short short8;
typedef __attribute__((ext_vector_type(4))) float f32x4;
typedef __attribute__((ext_vector_type(16))) float f32x16;
typedef __attribute__((ext_vector_type(2))) unsigned int uswap2;

#define GLDS(gp, lp) __builtin_amdgcn_global_load_lds(                        \
    (const __attribute__((address_space(1))) void*)(gp),                      \
    (__attribute__((address_space(3))) void*)(lp), 16, 0, 0)

__device__ __forceinline__ float bf2f(unsigned short u) {
    union { unsigned int i; float f; } v; v.i = ((unsigned int)u) << 16; return v.f;
}
__device__ __forceinline__ unsigned short f2bf(float f) {
    union { float f; unsigned int i; } v; v.f = f;
    unsigned int r = v.i + 0x7FFFu + ((v.i >> 16) & 1u);
    return (unsigned short)(r >> 16);
}
// HW packed f32x2 -> bf16x2: single v_cvt_pk_bf16_f32 (T12 recipe).
__device__ __forceinline__ unsigned int cvtpk(float a, float b) {
    unsigned int r;
    asm("v_cvt_pk_bf16_f32 %0, %1, %2" : "=v"(r) : "v"(a), "v"(b));
    return r;
}
__device__ __forceinline__ float fexp2(float x) {
#if __has_builtin(__builtin_amdgcn_exp2f)
    return __builtin_amdgcn_exp2f(x);
#else
    return exp2f(x);
#endif
}

// ---------------------------------------------------------------------------
// Fused prep (x4 vectorized): x cvt | 3 pointwise-weight cvts | masked-count.
// ---------------------------------------------------------------------------
__global__ __launch_bounds__(256)
void prep(const float* __restrict__ x,
          const float* __restrict__ pwq2, const float* __restrict__ pwk2,
          const float* __restrict__ pwv2, const int* __restrict__ mask,
          unsigned short* __restrict__ xb, unsigned short* __restrict__ pq,
          unsigned short* __restrict__ pk, unsigned short* __restrict__ pv,
          float* __restrict__ nmaskf)
{
    const size_t NE = (size_t)NTOK * DIMC;
    const size_t WE = (size_t)DIMC * DIMC;
    size_t i = ((size_t)blockIdx.x * 256 + threadIdx.x) * 4;
    const float* src = nullptr;
    unsigned short* dst = nullptr;
    if (i < NE) { src = x + i; dst = xb + i; }
    else if ((i -= NE) < WE) { src = pwq2 + i; dst = pq + i; }
    else if ((i -= WE) < WE) { src = pwk2 + i; dst = pk + i; }
    else if ((i -= WE) < WE) { src = pwv2 + i; dst = pv + i; }
    else {
        // masked-token count per batch (token index i, wave fully within one b)
        i -= WE;
        int4 m = *(const int4*)(mask + i);
        int cnt = (m.x == 0) + (m.y == 0) + (m.z == 0) + (m.w == 0);
#pragma unroll
        for (int off = 32; off; off >>= 1) cnt += __shfl_down(cnt, off, 64);
        if ((threadIdx.x & 63) == 0 && cnt)
            atomicAdd(&nmaskf[i >> 11], (float)cnt);
        return;
    }
    float4 v = *(const float4*)src;
    ushort4 o;
    o.x = f2bf(v.x); o.y = f2bf(v.y); o.z = f2bf(v.z); o.w = f2bf(v.w);
    *(ushort4*)dst = o;
}

// ---------------------------------------------------------------------------
// W [in][out] fp32 -> Wt [out][in] bf16, batched over 4 weights (z)
// ---------------------------------------------------------------------------
__global__ __launch_bounds__(256)
void transpose_cvt4(const float* __restrict__ W0, const float* __restrict__ W1,
                    const float* __restrict__ W2, const float* __restrict__ W3,
                    unsigned short* __restrict__ T0, unsigned short* __restrict__ T1,
                    unsigned short* __restrict__ T2, unsigned short* __restrict__ T3)
{
    int z = blockIdx.z;
    const float* W = z == 0 ? W0 : z == 1 ? W1 : z == 2 ? W2 : W3;
    unsigned short* Wt = z == 0 ? T0 : z == 1 ? T1 : z == 2 ? T2 : T3;
    __shared__ float T[32][33];
    int i0 = blockIdx.y * 32, o0 = blockIdx.x * 32;
    int c = threadIdx.x & 31, r4 = threadIdx.x >> 5;
#pragma unroll
    for (int p = 0; p < 4; ++p) {
        int r = r4 + p * 8;
        T[r][c] = W[(size_t)(i0 + r) * DIMC + o0 + c];
    }
    __syncthreads();
#pragma unroll
    for (int p = 0; p < 4; ++p) {
        int r = r4 + p * 8;
        Wt[(size_t)(o0 + r) * DIMC + i0 + c] = f2bf(T[c][r]);
    }
}

// ---------------------------------------------------------------------------
// bf16 MFMA GEMM core v5 (R6-verified BEST): 32x32x16 MFMA, BK=64,
// DOUBLE-BUFFERED minimum-2-phase order: issue next tile's 8 GLDS BEFORE
// computing current tile, ONE __syncthreads per K-step (== vmcnt(0)+barrier,
// compiler-safe). Loads get the whole ds_read+MFMA span to land; barrier
// count halves vs single-buffered. NO sched_barrier(0), NO counted vmcnt
// (m141 / R2 / R7 lessons: counted pipelines on coarse phases regress).
// LDS 64 KB. 128B-row LDS, 8-slot XOR chunk swizzle (conflict-free b128).
// C/D layout: col=lane&31, row=(reg&3)+8*(reg>>2)+4*(lane>>5).
// ---------------------------------------------------------------------------
template<bool SILU, bool F32OUT>
__device__ __forceinline__
void gemm_core(const unsigned short* __restrict__ A,
               const unsigned short* __restrict__ Bt,
               const float* __restrict__ bias, void* __restrict__ Cout,
               int m0, int n0)
{
    __shared__ unsigned short As[2][128 * 64];
    __shared__ unsigned short Bs[2][128 * 64];
    const int tid = threadIdx.x;
    const int lane = tid & 63;
    const int l32 = lane & 31, hi = lane >> 5;
    const int wave = tid >> 6;
    const int wm = (wave & 1) * 64, wn = (wave >> 1) * 64;
    const int K = DIMC, N = DIMC;

    f32x16 acc[2][2];
#pragma unroll
    for (int tm = 0; tm < 2; ++tm)
#pragma unroll
        for (int tn = 0; tn < 2; ++tn) acc[tm][tn] = (f32x16)(0.0f);

    // staging: 1024 16B-chunk slots per matrix; thread covers slots
    // {tid, 256+tid, 512+tid, 768+tid}. slot s -> row=s>>3, cslot=s&7;
    // LDS dest = s*16B (linear); global source chunk = cslot ^ (row&7).
    int srow[4], ssrc[4], sdst[4];
#pragma unroll
    for (int p = 0; p < 4; ++p) {
        int s = p * 256 + tid;
        srow[p] = s >> 3;
        ssrc[p] = ((s & 7) ^ (srow[p] & 7)) * 8;
        sdst[p] = s * 8;
    }

    auto stage = [&](int buf, int k0) {
#pragma unroll
        for (int p = 0; p < 4; ++p)
            GLDS(A  + (size_t)(m0 + srow[p]) * K + k0 + ssrc[p], &As[buf][sdst[p]]);
#pragma unroll
        for (int p = 0; p < 4; ++p)
            GLDS(Bt + (size_t)(n0 + srow[p]) * K + k0 + ssrc[p], &Bs[buf][sdst[p]]);
    };

    stage(0, 0);          // prologue
    __syncthreads();      // drains prologue loads, publishes buf0

    auto body = [&](int k0, int cur) {
        if (k0 + 64 < K) stage(cur ^ 1, k0 + 64);   // prefetch FIRST
#pragma unroll
        for (int ks = 0; ks < 4; ++ks) {
            const int cb = ks * 2 + hi;              // k-chunk index 0..7
            short8 af[2], bf[2];
#pragma unroll
            for (int tm = 0; tm < 2; ++tm) {
                int row = wm + tm * 32 + l32;
                int slot = cb ^ (row & 7);
                af[tm] = *(const short8*)(&As[cur][row * 64 + slot * 8]);
            }
#pragma unroll
            for (int tn = 0; tn < 2; ++tn) {
                int row = wn + tn * 32 + l32;
                int slot = cb ^ (row & 7);
                bf[tn] = *(const short8*)(&Bs[cur][row * 64 + slot * 8]);
            }
#pragma unroll
            for (int tm = 0; tm < 2; ++tm)
#pragma unroll
                for (int tn = 0; tn < 2; ++tn)
                    acc[tm][tn] = __builtin_amdgcn_mfma_f32_32x32x16_bf16(
                        af[tm], bf[tn], acc[tm][tn], 0, 0, 0);
        }
        __syncthreads();   // drains prefetch (vmcnt 0) + publishes; reads of
                           // cur are complete (consumed by MFMAs above)
    };

    for (int k0 = 0; k0 < K; k0 += 128) {
        body(k0, 0);
        body(k0 + 64, 1);
    }

#pragma unroll
    for (int tn = 0; tn < 2; ++tn) {
        int ncol = n0 + wn + tn * 32 + l32;
        float bval = bias[ncol];
#pragma unroll
        for (int tm = 0; tm < 2; ++tm) {
#pragma unroll
            for (int r = 0; r < 16; ++r) {
                int mrow = m0 + wm + tm * 32 + (r & 3) + 8 * (r >> 2) + 4 * hi;
                float v = acc[tm][tn][r] + bval;
                if (SILU) v = v / (1.0f + __expf(-v));
                if (F32OUT)
                    ((float*)Cout)[(size_t)mrow * N + ncol] = v;
                else
                    ((unsigned short*)Cout)[(size_t)mrow * N + ncol] = f2bf(v);
            }
        }
    }
}

// XCD-aware bijective chunked swizzle (T1): consecutive remapped tiles land
// on the same XCD's L2 (HW round-robins linear wgid % 8). Valid: nwg % 8 == 0.
__device__ __forceinline__ int xcd_swz(int lin, int nwg) {
    return (lin & 7) * (nwg >> 3) + (lin >> 3);
}

__global__ __launch_bounds__(256)
void gemm_qkv(const unsigned short* A,
              const unsigned short* B0, const unsigned short* B1, const unsigned short* B2,
              const float* b0, const float* b1, const float* b2,
              unsigned short* C0, unsigned short* C1, unsigned short* C2)
{
    const int gy = NTOK / 128;                       // 64
    int lin = blockIdx.x + 8 * (blockIdx.y + gy * blockIdx.z);
    int t = xcd_swz(lin, 8 * gy * 3);
    int zz = t / (8 * gy); int rem = t - zz * 8 * gy;
    int m0 = (rem >> 3) * 128, n0 = (rem & 7) * 128;
    gemm_core<true, false>(A, zz == 0 ? B0 : zz == 1 ? B1 : B2,
                           zz == 0 ? b0 : zz == 1 ? b1 : b2,
                           zz == 0 ? C0 : zz == 1 ? C1 : C2, m0, n0);
}

__global__ __launch_bounds__(256)
void gemm_pw(const unsigned short* A0, const unsigned short* A1, const unsigned short* A2,
             const unsigned short* B0, const unsigned short* B1, const unsigned short* B2,
             const float* b0, const float* b1, const float* b2,
             unsigned short* C0, unsigned short* C1, unsigned short* C2)
{
    const int gy = NTOK / 128;
    int lin = blockIdx.x + 8 * (blockIdx.y + gy * blockIdx.z);
    int t = xcd_swz(lin, 8 * gy * 3);
    int zz = t / (8 * gy); int rem = t - zz * 8 * gy;
    int m0 = (rem >> 3) * 128, n0 = (rem & 7) * 128;
    gemm_core<false, false>(zz == 0 ? A0 : zz == 1 ? A1 : A2,
                            zz == 0 ? B0 : zz == 1 ? B1 : B2,
                            zz == 0 ? b0 : zz == 1 ? b1 : b2,
                            zz == 0 ? C0 : zz == 1 ? C1 : C2, m0, n0);
}

__global__ __launch_bounds__(256)
void gemm_wo(const unsigned short* A, const unsigned short* Bt,
             const float* bias, float* C)
{
    const int gy = NTOK / 128;
    int lin = blockIdx.x + 8 * blockIdx.y;
    int t = xcd_swz(lin, 8 * gy);
    int m0 = (t >> 3) * 128, n0 = (t & 7) * 128;
    gemm_core<false, true>(A, Bt, bias, C, m0, n0);
}

// ---------------------------------------------------------------------------
// Depthwise conv k=3 pad=1 over seq + bias, 8 channels/thread (short8),
// batched over q/k/v (blockIdx.y)
// ---------------------------------------------------------------------------
__global__ __launch_bounds__(256)
void dwconv3(const unsigned short* __restrict__ qb, const unsigned short* __restrict__ kb,
             const unsigned short* __restrict__ vb,
             const float* __restrict__ dwq, const float* __restrict__ dwbq,
             const float* __restrict__ dwk, const float* __restrict__ dwbk,
             const float* __restrict__ dwv, const float* __restrict__ dwbv,
             unsigned short* __restrict__ o0, unsigned short* __restrict__ o1,
             unsigned short* __restrict__ o2)
{
    int z = blockIdx.y;
    const unsigned short* X = z == 0 ? qb : z == 1 ? kb : vb;
    const float* dw  = z == 0 ? dwq  : z == 1 ? dwk  : dwv;
    const float* dwb = z == 0 ? dwbq : z == 1 ? dwbk : dwbv;
    unsigned short* Y = z == 0 ? o0 : z == 1 ? o1 : o2;

    int i8 = (blockIdx.x * 256 + threadIdx.x) * 8;
    int c = i8 & (DIMC - 1);
    int s = (i8 >> 10) & (SEQ - 1);
    short8 zero = {};
    short8 xc8 = *(const short8*)(X + i8);
    short8 xm8 = (s > 0)       ? *(const short8*)(X + i8 - DIMC) : zero;
    short8 xp8 = (s < SEQ - 1) ? *(const short8*)(X + i8 + DIMC) : zero;
    short8 y;
#pragma unroll
    for (int j = 0; j < 8; ++j) {
        float w0 = dw[(c + j) * 3 + 0], w1 = dw[(c + j) * 3 + 1], w2 = dw[(c + j) * 3 + 2];
        float r = fmaf(w0, bf2f((unsigned short)xm8[j]),
                  fmaf(w1, bf2f((unsigned short)xc8[j]),
                  fmaf(w2, bf2f((unsigned short)xp8[j]), dwb[c + j])));
        y[j] = (short)f2bf(r);
    }
    *(short8*)(Y + i8) = y;
}

// ---------------------------------------------------------------------------
// Per-token L2 normalize IN PLACE (scales folded into bf16 q/k).
// y=0: q gets 0.125*log2e/||q|| ; y=1: k gets mask/||k|| (masked K row -> 0,
// so its score is exactly 0 and p = exp2(0) = 1, corrected via nmask in attn).
// ---------------------------------------------------------------------------
__global__ __launch_bounds__(256)
void rownorms(unsigned short* __restrict__ qb, unsigned short* __restrict__ kb,
              const int* __restrict__ mask)
{
    unsigned short* X = (blockIdx.y ? kb : qb) + (size_t)blockIdx.x * DIMC;
    ushort4 v = ((const ushort4*)X)[threadIdx.x];
    float f0 = bf2f(v.x), f1 = bf2f(v.y), f2 = bf2f(v.z), f3 = bf2f(v.w);
    float s = f0 * f0 + f1 * f1 + f2 * f2 + f3 * f3;
#pragma unroll
    for (int off = 32; off; off >>= 1) s += __shfl_down(s, off, 64);
    __shared__ float part[4];
    if ((threadIdx.x & 63) == 0) part[threadIdx.x >> 6] = s;
    __syncthreads();
    float tot = part[0] + part[1] + part[2] + part[3];
    float post = blockIdx.y ? (mask[blockIdx.x] ? 1.0f : 0.0f)
                            : 0.125f * 1.44269504088896f;
    float inv = post / fmaxf(sqrtf(tot), 1e-12f);
    ushort4 o;
    o.x = f2bf(f0 * inv); o.y = f2bf(f1 * inv);
    o.z = f2bf(f2 * inv); o.w = f2bf(f3 * inv);
    ((ushort4*)X)[threadIdx.x] = o;
}

// ---------------------------------------------------------------------------
// V [B,S,C] bf16 -> Vt [B*H][64][SEQ] bf16 (per-head transpose), masked V rows
// zeroed so they contribute nothing to P@V.
// ---------------------------------------------------------------------------
__global__ __launch_bounds__(256)
void vtrans(const unsigned short* __restrict__ V, const int* __restrict__ mask,
            unsigned short* __restrict__ Vt)
{
    __shared__ unsigned short T[64][65];
    int st = blockIdx.x, bh = blockIdx.y;
    int b = bh >> 4, h = bh & 15;
    int tid = threadIdx.x;
#pragma unroll
    for (int t = 0; t < 16; ++t) {
        int o = t * 256 + tid; int r = o >> 6, c = o & 63;
        int srow = b * SEQ + st * 64 + r;
        T[r][c] = mask[srow] ? V[(size_t)srow * DIMC + h * HD + c] : (unsigned short)0;
    }
    __syncthreads();
#pragma unroll
    for (int t = 0; t < 16; ++t) {
        int o = t * 256 + tid; int r = o >> 6, c = o & 63;
        Vt[(size_t)bh * HD * SEQ + (size_t)r * SEQ + st * 64 + c] = T[c][r];
    }
}

// ---------------------------------------------------------------------------
// Flash attention v7 (R6/R8-verified): 64 q-rows per wave, K/V frags hoisted
// once per body and reused by both q-halves, in-register softmax (T12).
// ---------------------------------------------------------------------------
__global__ __launch_bounds__(256, 2)
void attn_mfma7(const unsigned short* __restrict__ Q,
                const unsigned short* __restrict__ Km,
                const unsigned short* __restrict__ Vt,
                const float* __restrict__ nmaskf,
                unsigned short* __restrict__ O)
{
    __shared__ unsigned short Ksb[2][64 * 64];   // [k][d], chunk-swizzled
    __shared__ unsigned short Vsb[2][64 * 64];   // [d][k], chunk-swizzled
    const int tid = threadIdx.x, lane = tid & 63, wave = tid >> 6;
    const int l32 = lane & 31, hi = lane >> 5;
    int lin = blockIdx.x + 8 * blockIdx.y;
    int t0 = xcd_swz(lin, 8 * BATCH * HEADS);
    const int qt = t0 & 7, bh = t0 >> 3;
    const int b = bh >> 4, h = bh & 15;
    const size_t qkbase = (size_t)b * SEQ * DIMC + (size_t)h * HD;
    const size_t vtbase = (size_t)bh * HD * SEQ;
    const int qrowbase = qt * 256 + wave * 64;   // wave owns 64 q rows
    const int NT = SEQ / 64;

    short8 aq[2][4];
#pragma unroll
    for (int g = 0; g < 2; ++g)
#pragma unroll
        for (int d = 0; d < 4; ++d)
            aq[g][d] = *(const short8*)(Q + qkbase +
                (size_t)(qrowbase + g * 32 + l32) * DIMC + d * 16 + hi * 8);

    short8 vone;
#pragma unroll
    for (int i = 0; i < 8; ++i) vone[i] = (short)0x3F80;   // bf16 1.0

    const int sA = tid,        rA = sA >> 3, cA = (sA & 7) ^ (rA & 7);
    const int sB = 256 + tid,  rB = sB >> 3, cB = (sB & 7) ^ (rB & 7);

    const unsigned short* KmP = Km + qkbase;
    const unsigned short* VtP = Vt + vtbase;

    GLDS(KmP + (size_t)rA * DIMC + cA * 8, Ksb[0] + sA * 8);
    GLDS(KmP + (size_t)rB * DIMC + cB * 8, Ksb[0] + sB * 8);
    GLDS(VtP + (size_t)rA * SEQ + cA * 8,  Vsb[0] + sA * 8);
    GLDS(VtP + (size_t)rB * SEQ + cB * 8,  Vsb[0] + sB * 8);

    f32x16 oacc[2][2], lacc[2];
#pragma unroll
    for (int g = 0; g < 2; ++g) {
        oacc[g][0] = (f32x16)(0.0f); oacc[g][1] = (f32x16)(0.0f);
        lacc[g] = (f32x16)(0.0f);
    }

    auto body = [&](int kt, int cur) {
        __syncthreads();   // publishes buffer `cur`

        if (kt + 1 < NT) {
            const unsigned short* kn = KmP + (size_t)(kt + 1) * 64 * DIMC;
            const unsigned short* vn = VtP + (size_t)(kt + 1) * 64;
            GLDS(kn + (size_t)rA * DIMC + cA * 8, Ksb[cur ^ 1] + sA * 8);
            GLDS(kn + (size_t)rB * DIMC + cB * 8, Ksb[cur ^ 1] + sB * 8);
            GLDS(vn + (size_t)rA * SEQ + cA * 8,  Vsb[cur ^ 1] + sA * 8);
            GLDS(vn + (size_t)rB * SEQ + cB * 8,  Vsb[cur ^ 1] + sB * 8);
        }

        const unsigned short* Ks = Ksb[cur];
        const unsigned short* Vs = Vsb[cur];

        // hoist ALL K A-frags and V B-frags ONCE: reused by both q-halves.
        short8 ak[2][4], bv[4][2];
#pragma unroll
        for (int t = 0; t < 2; ++t) {
            const int row = t * 32 + l32, sw = row & 7;
#pragma unroll
            for (int d = 0; d < 4; ++d)
                ak[t][d] = *(const short8*)(Ks + row * 64 + (((d * 2 + hi) ^ sw)) * 8);
        }
#pragma unroll
        for (int s = 0; s < 4; ++s)
#pragma unroll
            for (int td = 0; td < 2; ++td) {
                const int row = td * 32 + l32, sw = row & 7;
                bv[s][td] = *(const short8*)(Vs + row * 64 + (((s * 2 + hi) ^ sw)) * 8);
            }

#pragma unroll
        for (int g = 0; g < 2; ++g) {
            f32x16 sacc[2];
            sacc[0] = (f32x16)(0.0f); sacc[1] = (f32x16)(0.0f);
            __builtin_amdgcn_s_setprio(1);
#pragma unroll
            for (int t = 0; t < 2; ++t)
#pragma unroll
                for (int d = 0; d < 4; ++d)
                    sacc[t] = __builtin_amdgcn_mfma_f32_32x32x16_bf16(
                        ak[t][d], aq[g][d], sacc[t], 0, 0, 0);
            __builtin_amdgcn_s_setprio(0);

#pragma unroll
            for (int t = 0; t < 2; ++t)
#pragma unroll
                for (int r = 0; r < 16; ++r)
                    sacc[t][r] = fexp2(sacc[t][r]);

#pragma unroll
            for (int s = 0; s < 4; ++s) {
                const int t = s >> 1, u8 = (s & 1) * 8;
                unsigned int a0 = cvtpk(sacc[t][u8 + 0], sacc[t][u8 + 1]);
                unsigned int b0 = cvtpk(sacc[t][u8 + 4], sacc[t][u8 + 5]);
                unsigned int a1 = cvtpk(sacc[t][u8 + 2], sacc[t][u8 + 3]);
                unsigned int b1 = cvtpk(sacc[t][u8 + 6], sacc[t][u8 + 7]);
                uswap2 r0 = __builtin_amdgcn_permlane32_swap(a0, b0, false, false);
                uswap2 r1 = __builtin_amdgcn_permlane32_swap(a1, b1, false, false);
                union { unsigned int u[4]; short8 v; } pw;
                pw.u[0] = r0.x; pw.u[1] = r1.x; pw.u[2] = r0.y; pw.u[3] = r1.y;
                const short8 pa = pw.v;

                __builtin_amdgcn_s_setprio(1);
#pragma unroll
                for (int td = 0; td < 2; ++td)
                    oacc[g][td] = __builtin_amdgcn_mfma_f32_32x32x16_bf16(
                        pa, bv[s][td], oacc[g][td], 0, 0, 0);
                lacc[g] = __builtin_amdgcn_mfma_f32_32x32x16_bf16(
                    pa, vone, lacc[g], 0, 0, 0);
                __builtin_amdgcn_s_setprio(0);
            }
        }
    };

    for (int kt = 0; kt < NT; kt += 2) {
        body(kt, 0);
        body(kt + 1, 1);
    }

    const float nm = nmaskf[b];
#pragma unroll
    for (int g = 0; g < 2; ++g)
#pragma unroll
        for (int r = 0; r < 16; ++r) {
            float inv = 1.0f / (lacc[g][r] - nm);
            int grow = qrowbase + g * 32 + (r & 3) + 8 * (r >> 2) + 4 * hi;
#pragma unroll
            for (int t = 0; t < 2; ++t)
                O[(size_t)(b * SEQ + grow) * DIMC + h * HD + t * 32 + l32] =
                    f2bf(oacc[g][t][r] * inv);
        }
}

// ---------------------------------------------------------------------------
extern "C" void kernel_launch(void* const* d_in, const int* in_sizes, int n_in,
                              void* d_out, int out_size, void* d_ws, size_t ws_size,
                              hipStream_t stream)
{
    const float* x    = (const float*)d_in[0];
    const int*   mask = (const int*)  d_in[1];
    const float* wq   = (const float*)d_in[2];
    const float* bq   = (const float*)d_in[3];
    const float* dwq  = (const float*)d_in[4];
    const float* dwbq = (const float*)d_in[5];
    const float* pwq  = (const float*)d_in[6];
    const float* pwbq = (const float*)d_in[7];
    const float* wk   = (const float*)d_in[8];
    const float* bk   = (const float*)d_in[9];
    const float* dwk  = (const float*)d_in[10];
    const float* dwbk = (const float*)d_in[11];
    const float* pwk  = (const float*)d_in[12];
    const float* pwbk = (const float*)d_in[13];
    const float* wv   = (const float*)d_in[14];
    const float* bv   = (const float*)d_in[15];
    const float* dwv  = (const float*)d_in[16];
    const float* dwbv = (const float*)d_in[17];
    const float* pwv  = (const float*)d_in[18];
    const float* pwbv = (const float*)d_in[19];
    const float* wo   = (const float*)d_in[20];
    const float* bo   = (const float*)d_in[21];

    float* out = (float*)d_out;
    const size_t NE = (size_t)NTOK * DIMC;
    const size_t WE = (size_t)DIMC * DIMC;
    unsigned short* xb  = (unsigned short*)d_ws;   // x bf16; later dwconv-q out; later attn out
    unsigned short* qb  = xb + NE;
    unsigned short* kb  = qb + NE;
    unsigned short* vb  = kb + NE;
    unsigned short* tbA = vb + NE;
    unsigned short* tbB = tbA + NE;
    unsigned short* vt  = tbB + NE;
    unsigned short* wtq = vt + NE;
    unsigned short* wtk = wtq + WE;
    unsigned short* wtv = wtk + WE;
    unsigned short* wto = wtv + WE;
    unsigned short* pq  = wto + WE;
    unsigned short* pk  = pq + WE;
    unsigned short* pv  = pk + WE;
    float* nmaskf = (float*)(pv + WE);

    const dim3 tgrid(32, 32, 4);
    const dim3 ggrid3(DIMC / 128, NTOK / 128, 3);
    const dim3 ggrid(DIMC / 128, NTOK / 128);
    const dim3 vgrid(SEQ / 64, BATCH * HEADS);
    const dim3 agrid(SEQ / 256, BATCH * HEADS);
    const int pblk = (int)((NE + 3 * WE + NTOK) / 4 / 256);
    const int dblk = (int)(NE / 8 / 256);

    hipMemsetAsync(nmaskf, 0, BATCH * sizeof(float), stream);
    prep<<<pblk, 256, 0, stream>>>(x, pwq, pwk, pwv, mask, xb, pq, pk, pv, nmaskf);
    transpose_cvt4<<<tgrid, 256, 0, stream>>>(wq, wk, wv, wo, wtq, wtk, wtv, wto);

    // q/k/v = silu(x @ w + b), batched
    gemm_qkv<<<ggrid3, 256, 0, stream>>>(xb, wtq, wtk, wtv, bq, bk, bv, qb, kb, vb);

    // depthwise (batched) -> {xb, tbA, tbB}; pointwise (batched) -> back to q/k/v
    dwconv3<<<dim3(dblk, 3), 256, 0, stream>>>(qb, kb, vb, dwq, dwbq, dwk, dwbk,
                                               dwv, dwbv, xb, tbA, tbB);
    gemm_pw<<<ggrid3, 256, 0, stream>>>(xb, tbA, tbB, pq, pk, pv,
                                        pwbq, pwbk, pwbv, qb, kb, vb);

    // in-place l2 normalize q (0.125*log2e folded) and k (mask folded)
    rownorms<<<dim3(NTOK, 2), 256, 0, stream>>>(qb, kb, mask);

    // V transpose (masked rows zeroed), attention (out -> xb), final projection
    vtrans<<<vgrid, 256, 0, stream>>>(vb, mask, vt);
    attn_mfma7<<<agrid, 256, 0, stream>>>(qb, kb, vt, nmaskf, xb);
    gemm_wo<<<ggrid, 256, 0, stream>>>(xb, wto, bo, out);
}